// Round 3
// baseline (50.696 us; speedup 1.0000x reference)
//
#include <hip/hip_runtime.h>
#include <math.h>

#define NB   64
#define CCH  512
#define SZ   28
#define HW   784          // 28*28
#define NCHUNK 8
#define CPC  (CCH / NCHUNK)   // 64 channels per chunk
#define Q4   (HW / 4)         // 196 float4 per row

typedef float f4 __attribute__((ext_vector_type(4)));  // native vec for nontemporal builtins

// output layout (floats):
//   [0, 100352)          relative_coord_total  [64,784,2]
//   [100352, 100480)     basic_anchor          [64,2]
//   [100480, ...)        position_weight       [64,784,784]
#define OFF_ANCHOR 100352
#define OFF_PW     100480

// ---------------- K1: partial channel sums ----------------
// grid (NCHUNK, NB), block 256. Each block sums 64 channels for one sample.
__global__ __launch_bounds__(256) void k_partial(const float* __restrict__ x,
                                                 float* __restrict__ partial) {
    const int chunk = blockIdx.x;
    const int n     = blockIdx.y;
    const int t     = threadIdx.x;
    if (t >= Q4) return;

    const f4* xp = (const f4*)(x + (size_t)n * CCH * HW + (size_t)chunk * CPC * HW) + t;
    f4 acc = (f4)(0.f);
    #pragma unroll 4
    for (int c = 0; c < CPC; ++c) {
        f4 v = __builtin_nontemporal_load(xp + (size_t)c * Q4);
        acc += v;
    }
    *((f4*)(partial + ((size_t)n * NCHUNK + chunk) * HW) + t) = acc;
}

// ---------------- K2: fused reduce + outer product (+ coords on tile 0) ----
// grid (98, NB), block 256; 8 output rows per block.
#define ROWS 8
__global__ __launch_bounds__(256) void k_fused(const float* __restrict__ partial,
                                               float* __restrict__ out) {
    const int tile = blockIdx.x;   // 0..97
    const int n    = blockIdx.y;
    const int t    = threadIdx.x;

    __shared__ float row[HW];      // pw = mask / C
    __shared__ float red[256];
    __shared__ int   redi[256];

    float local = 0.f;
    if (t < Q4) {
        f4 acc = (f4)(0.f);
        #pragma unroll
        for (int ch = 0; ch < NCHUNK; ++ch) {
            acc += *((const f4*)(partial + ((size_t)n * NCHUNK + ch) * HW) + t);
        }
        acc *= (1.0f / (float)CCH);
        ((f4*)row)[t] = acc;
        local = acc.x + acc.y + acc.z + acc.w;
    }
    __syncthreads();

    // rank-1 outer product: 8 rows, nontemporal float4 stores
    if (t < Q4) {
        f4 v = ((f4*)row)[t];
        float* obase = out + OFF_PW + ((size_t)n * HW + (size_t)tile * ROWS) * HW;
        #pragma unroll
        for (int r = 0; r < ROWS; ++r) {
            float a = row[tile * ROWS + r];
            f4 w = v * a;
            __builtin_nontemporal_store(w, (f4*)(obase + (size_t)r * HW) + t);
        }
    }

    if (tile != 0) return;

    // ---- tile 0 only: threshold, argmax, anchor, relative coords ----
    // mean of pw row (threshold comparison is scale-invariant under /C)
    red[t] = local;
    __syncthreads();
    for (int s = 128; s > 0; s >>= 1) {
        if (t < s) red[t] += red[t + s];
        __syncthreads();
    }
    const float thr = red[0] * (1.0f / HW);
    __syncthreads();

    float bv = -INFINITY; int bp = HW;
    for (int p = t; p < HW; p += 256) {
        float m = row[p];
        float s = (m > thr) ? m : 0.0f;
        if (s > bv) { bv = s; bp = p; }     // ascending p -> first within thread
    }
    red[t] = bv; redi[t] = bp;
    __syncthreads();
    for (int s = 128; s > 0; s >>= 1) {
        if (t < s) {
            float ov = red[t + s]; int op = redi[t + s];
            if (ov > red[t] || (ov == red[t] && op < redi[t])) { red[t] = ov; redi[t] = op; }
        }
        __syncthreads();
    }
    const int   idx = redi[0];
    const float ai  = (float)(idx / SZ);
    const float aj  = (float)(idx % SZ);

    if (t == 0) {
        out[OFF_ANCHOR + n * 2 + 0] = ai;
        out[OFF_ANCHOR + n * 2 + 1] = aj;
    }

    const float inv_sz = 1.0f / (float)SZ;
    const float inv_pi = 0.31830988618367444f;   // 1/pi
    for (int p = t; p < HW; p += 256) {
        float ci = ((float)(p / SZ) - ai) * inv_sz;
        float cj = ((float)(p % SZ) - aj) * inv_sz;
        float dist = sqrtf(ci * ci + cj * cj);
        float ang  = (atan2f(cj, ci) * inv_pi + 1.0f) * 0.5f;
        ((float2*)out)[(size_t)n * HW + p] = make_float2(dist, ang);
    }
}

extern "C" void kernel_launch(void* const* d_in, const int* in_sizes, int n_in,
                              void* d_out, int out_size, void* d_ws, size_t ws_size,
                              hipStream_t stream) {
    const float* x = (const float*)d_in[0];
    float* out = (float*)d_out;

    // workspace: partials [NB*NCHUNK*HW]  (~1.6 MB)
    float* partial = (float*)d_ws;

    k_partial<<<dim3(NCHUNK, NB), 256, 0, stream>>>(x, partial);
    k_fused  <<<dim3(98, NB),     256, 0, stream>>>(partial, out);
}

// Round 4
// 47.457 us; speedup vs baseline: 1.0682x; 1.0682x over previous
//
#include <hip/hip_runtime.h>
#include <math.h>

#define NB     64
#define CCH    512
#define SZ     28
#define HW     784            // 28*28
#define NCHUNK 8
#define CPC    (CCH / NCHUNK) // 64 channels per chunk
#define Q4     (HW / 4)       // 196 float4 per row
#define ROWS   8              // output rows per tile
#define NTILE  (HW / ROWS)    // 98 tiles per sample
#define GPB    8              // outer-product groups per sample

typedef float f4 __attribute__((ext_vector_type(4)));

// output layout (floats):
//   [0, 100352)          relative_coord_total  [64,784,2]
//   [100352, 100480)     basic_anchor          [64,2]
//   [100480, ...)        position_weight       [64,784,784]
#define OFF_ANCHOR 100352
#define OFF_PW     100480

// ---------------- K1: partial channel sums ----------------
// grid (NCHUNK, NB), block 256. Each block sums 64 channels for one sample.
__global__ __launch_bounds__(256) void k_partial(const float* __restrict__ x,
                                                 float* __restrict__ partial) {
    const int chunk = blockIdx.x;
    const int n     = blockIdx.y;
    const int t     = threadIdx.x;
    if (t >= Q4) return;

    const f4* xp = (const f4*)(x + (size_t)n * CCH * HW + (size_t)chunk * CPC * HW) + t;
    f4 acc = (f4)(0.f);
    #pragma unroll 4
    for (int c = 0; c < CPC; ++c) acc += xp[(size_t)c * Q4];
    ((f4*)(partial + ((size_t)n * NCHUNK + chunk) * HW))[t] = acc;
}

// ---------------- K2: grouped reduce + outer product (+ coords on g==0) ----
// grid (GPB, NB), block 256. Each block reduces the 8 partial rows ONCE into
// LDS, then writes 12-13 tiles (8 rows each) of the rank-1 outer product.
// g==0 blocks additionally do threshold/argmax/anchor/coords.
__global__ __launch_bounds__(256) void k_outer(const float* __restrict__ partial,
                                               float* __restrict__ out) {
    const int g = blockIdx.x;   // 0..7
    const int n = blockIdx.y;
    const int t = threadIdx.x;

    __shared__ float row[HW];   // pw = mask / C
    __shared__ float red[256];
    __shared__ int   redi[256];

    float local = 0.f;
    if (t < Q4) {
        f4 acc = (f4)(0.f);
        #pragma unroll
        for (int ch = 0; ch < NCHUNK; ++ch)
            acc += ((const f4*)(partial + ((size_t)n * NCHUNK + ch) * HW))[t];
        acc *= (1.0f / (float)CCH);
        ((f4*)row)[t] = acc;
        local = acc.x + acc.y + acc.z + acc.w;
    }
    __syncthreads();

    // this group's tile range: 98 = 2*13 + 6*12
    const int t0 = g * 12 + (g < 2 ? g : 2);
    const int nt = (g < 2) ? 13 : 12;

    if (t < Q4) {
        f4 v = ((f4*)row)[t];
        for (int k = 0; k < nt; ++k) {
            const int tile = t0 + k;
            float* obase = out + OFF_PW + ((size_t)n * HW + (size_t)tile * ROWS) * HW;
            #pragma unroll
            for (int r = 0; r < ROWS; ++r) {
                float a = row[tile * ROWS + r];
                ((f4*)(obase + (size_t)r * HW))[t] = v * a;
            }
        }
    }

    if (g != 0) return;

    // ---- g==0 only: threshold, argmax, anchor, relative coords ----
    red[t] = local;
    __syncthreads();
    for (int s = 128; s > 0; s >>= 1) {
        if (t < s) red[t] += red[t + s];
        __syncthreads();
    }
    const float thr = red[0] * (1.0f / HW);
    __syncthreads();

    float bv = -INFINITY; int bp = HW;
    for (int p = t; p < HW; p += 256) {
        float m = row[p];
        float s = (m > thr) ? m : 0.0f;
        if (s > bv) { bv = s; bp = p; }     // ascending p -> first within thread
    }
    red[t] = bv; redi[t] = bp;
    __syncthreads();
    for (int s = 128; s > 0; s >>= 1) {
        if (t < s) {
            float ov = red[t + s]; int op = redi[t + s];
            if (ov > red[t] || (ov == red[t] && op < redi[t])) { red[t] = ov; redi[t] = op; }
        }
        __syncthreads();
    }
    const int   idx = redi[0];
    const float ai  = (float)(idx / SZ);
    const float aj  = (float)(idx % SZ);

    if (t == 0) {
        out[OFF_ANCHOR + n * 2 + 0] = ai;
        out[OFF_ANCHOR + n * 2 + 1] = aj;
    }

    const float inv_sz = 1.0f / (float)SZ;
    const float inv_pi = 0.31830988618367444f;   // 1/pi
    for (int p = t; p < HW; p += 256) {
        float ci = ((float)(p / SZ) - ai) * inv_sz;
        float cj = ((float)(p % SZ) - aj) * inv_sz;
        float dist = sqrtf(ci * ci + cj * cj);
        float ang  = (atan2f(cj, ci) * inv_pi + 1.0f) * 0.5f;
        ((float2*)out)[(size_t)n * HW + p] = make_float2(dist, ang);
    }
}

extern "C" void kernel_launch(void* const* d_in, const int* in_sizes, int n_in,
                              void* d_out, int out_size, void* d_ws, size_t ws_size,
                              hipStream_t stream) {
    const float* x = (const float*)d_in[0];
    float* out = (float*)d_out;

    // workspace: partials [NB*NCHUNK*HW]  (~1.6 MB)
    float* partial = (float*)d_ws;

    k_partial<<<dim3(NCHUNK, NB), 256, 0, stream>>>(x, partial);
    k_outer  <<<dim3(GPB,    NB), 256, 0, stream>>>(partial, out);
}